// Round 1
// baseline (1809.814 us; speedup 1.0000x reference)
//
#include <hip/hip_runtime.h>
#include <stdint.h>

typedef short s16x4 __attribute__((ext_vector_type(4)));
typedef short s16x8 __attribute__((ext_vector_type(8)));
typedef float f32x4 __attribute__((ext_vector_type(4)));

__device__ __forceinline__ short f2bf(float f) {
  unsigned u = __builtin_bit_cast(unsigned, f);
  u += 0x7fffu + ((u >> 16) & 1u);   // RNE
  return (short)(u >> 16);
}

__device__ __forceinline__ void gll16(const short* g, short* l) {
  __builtin_amdgcn_global_load_lds(
      (const __attribute__((address_space(1))) unsigned*)g,
      (__attribute__((address_space(3))) unsigned*)l, 16, 0, 0);
}

#define MFMA(a, b, c) __builtin_amdgcn_mfma_f32_16x16x32_bf16(a, b, c, 0, 0, 0)

// ---------------- pack x: NCHW f32 -> padded NHWC bf16 (16,66,66,512) ----------------
__global__ __launch_bounds__(256) void pack_x(const float* __restrict__ x, short* __restrict__ xp) {
  int b = blockIdx.x; int n = b >> 6; int h = b & 63;
  int t = threadIdx.x; int l = t & 63; int wv = t >> 6;
  const float* xs = x + (size_t)n * (512 * 4096) + h * 64 + l;
  short* xd = xp + (((size_t)n * 66 + (h + 1)) * 66 + (l + 1)) * 512;
  for (int c0 = wv * 8; c0 < 512; c0 += 32) {
    s16x8 v;
#pragma unroll
    for (int j = 0; j < 8; ++j) v[j] = f2bf(xs[(size_t)(c0 + j) * 4096]);
    *(s16x8*)(xd + c0) = v;
  }
}

// ---------------- pack conv weights: [co][ci][3][3] f32 -> [co][kyx*512+ci] bf16 ----------------
__global__ __launch_bounds__(256) void pack_w(const float* __restrict__ qw, const float* __restrict__ kvw,
                                              short* __restrict__ wqkv) {
  int co = blockIdx.x;  // 0..1535
  const float* src = (co < 512) ? (qw + (size_t)co * 4608) : (kvw + (size_t)(co - 512) * 4608);
  short* dst = wqkv + (size_t)co * 4608;
  for (int i = threadIdx.x; i < 4608; i += 256) {  // coalesced read, scattered 2B write (L2 merges)
    int ci = i / 9, kyx = i - ci * 9;
    dst[kyx * 512 + ci] = f2bf(src[i]);
  }
}

__global__ __launch_bounds__(256) void pack_pw(const float* __restrict__ pw, short* __restrict__ wp) {
  int i = blockIdx.x * 256 + threadIdx.x;  // grid 1024 * 256 = 262144
  wp[i] = f2bf(pw[i]);
}

// ---------------- fused qkv conv3x3 as implicit GEMM ----------------
// M = 65536 spatial (NHWC rows), N = 1536 out-channels, K = 4608 (kyx*512+ci)
// C[s][co] = sum_k A[s][k] * B[co][k];  A = im2col(xp NHWC padded), B = wqkv
__global__ __launch_bounds__(256, 2) void conv_gemm(const short* __restrict__ xp, const short* __restrict__ wqkv,
                                                    const float* __restrict__ qb, const float* __restrict__ kvb,
                                                    short* __restrict__ qkv) {
  __shared__ short Alds[128 * 32];
  __shared__ short Blds[128 * 32];
  int bid = blockIdx.x;
  int ntile = bid % 12, mtile = bid / 12;  // consecutive bids share the A panel
  int s0 = mtile * 128, co0 = ntile * 128;
  int t = threadIdx.x, l = t & 63, wv = t >> 6;
  int rl = l >> 2, kq = l & 3;

  int sA0 = s0 + wv * 16 + rl;
  int sA1 = sA0 + 64;
  auto abase = [&](int s) -> size_t {
    int n = s >> 12, h = (s >> 6) & 63, w = s & 63;
    return (((size_t)n * 66 + h) * 66 + w) * 512 + kq * 8;  // (ky=0,kx=0) corner in padded buf
  };
  size_t bA0 = abase(sA0), bA1 = abase(sA1);
  size_t bB0 = (size_t)(co0 + wv * 16 + rl) * 4608 + kq * 8;
  size_t bB1 = bB0 + (size_t)64 * 4608;
  short* lA0 = Alds + wv * 16 * 32;
  short* lA1 = Alds + (64 + wv * 16) * 32;
  short* lB0 = Blds + wv * 16 * 32;
  short* lB1 = Blds + (64 + wv * 16) * 32;

  int wm = wv >> 1, wn = wv & 1;
  int la = (wm * 64 + (l & 15)) * 32 + (l >> 4) * 8;
  int lb = (wn * 64 + (l & 15)) * 32 + (l >> 4) * 8;

  f32x4 acc[4][4];
#pragma unroll
  for (int i = 0; i < 4; ++i)
#pragma unroll
    for (int j = 0; j < 4; ++j) acc[i][j] = (f32x4){0.f, 0.f, 0.f, 0.f};

  for (int kyx = 0; kyx < 9; ++kyx) {
    int sh = ((kyx / 3) * 66 + (kyx % 3)) * 512;
    for (int cs = 0; cs < 16; ++cs) {
      int ao = sh + cs * 32;
      int bo = kyx * 512 + cs * 32;
      gll16(xp + bA0 + ao, lA0);
      gll16(xp + bA1 + ao, lA1);
      gll16(wqkv + bB0 + bo, lB0);
      gll16(wqkv + bB1 + bo, lB1);
      __syncthreads();
      s16x8 af[4], bf[4];
#pragma unroll
      for (int mt = 0; mt < 4; ++mt) af[mt] = *(const s16x8*)(Alds + la + mt * 16 * 32);
#pragma unroll
      for (int nt = 0; nt < 4; ++nt) bf[nt] = *(const s16x8*)(Blds + lb + nt * 16 * 32);
#pragma unroll
      for (int mt = 0; mt < 4; ++mt)
#pragma unroll
        for (int nt = 0; nt < 4; ++nt) acc[mt][nt] = MFMA(af[mt], bf[nt], acc[mt][nt]);
      __syncthreads();
    }
  }
#pragma unroll
  for (int mt = 0; mt < 4; ++mt) {
    int srow = s0 + wm * 64 + mt * 16 + ((l >> 4) << 2);
    int n = srow >> 12, sl = srow & 4095;
#pragma unroll
    for (int nt = 0; nt < 4; ++nt) {
      int col = co0 + wn * 64 + nt * 16 + (l & 15);
      float bias = (col < 512) ? qb[col] : kvb[col - 512];
      s16x4 v;
#pragma unroll
      for (int j = 0; j < 4; ++j) v[j] = f2bf(acc[mt][nt][j] + bias);
      *(s16x4*)(qkv + ((size_t)n * 1536 + col) * 4096 + sl) = v;  // NCHW bf16, 8B store
    }
  }
}

// ---------------- per-(n,ch) attention: O = softmax(Q K^T) V on 64x64 planes ----------------
__global__ __launch_bounds__(64) void attn(const short* __restrict__ qkv, short* __restrict__ o) {
  __shared__ short VT[64 * 72];  // V^T, pitch 72 (16B-aligned rows, 2-way banks)
  __shared__ short P[64 * 72];   // softmax(S) as [i][k]
  int slice = blockIdx.x;
  int n = slice >> 9, ch = slice & 511;
  const short* Q = qkv + ((size_t)n * 1536 + ch) * 4096;
  const short* K = qkv + ((size_t)n * 1536 + 512 + ch) * 4096;
  const short* V = qkv + ((size_t)n * 1536 + 1024 + ch) * 4096;
  int l = threadIdx.x;
  int r16 = l & 15, hi = l >> 4;

  // transpose V into LDS: lane owns row l of V -> column l of VT
  s16x8 vr[8];
#pragma unroll
  for (int j = 0; j < 8; ++j) vr[j] = *(const s16x8*)(V + l * 64 + j * 8);
#pragma unroll
  for (int a = 0; a < 8; ++a)
#pragma unroll
    for (int e = 0; e < 8; ++e) VT[(a * 8 + e) * 72 + l] = vr[a][e];

  // S^T = gemm_bt(K, Q): D[m=krow][n=i], contraction over w
  f32x4 st[4][4];
#pragma unroll
  for (int i = 0; i < 4; ++i)
#pragma unroll
    for (int j = 0; j < 4; ++j) st[i][j] = (f32x4){0.f, 0.f, 0.f, 0.f};
#pragma unroll
  for (int kc = 0; kc < 2; ++kc) {
    s16x8 kf[4], qf[4];
#pragma unroll
    for (int mt = 0; mt < 4; ++mt) kf[mt] = *(const s16x8*)(K + (mt * 16 + r16) * 64 + kc * 32 + hi * 8);
#pragma unroll
    for (int nt = 0; nt < 4; ++nt) qf[nt] = *(const s16x8*)(Q + (nt * 16 + r16) * 64 + kc * 32 + hi * 8);
#pragma unroll
    for (int mt = 0; mt < 4; ++mt)
#pragma unroll
      for (int nt = 0; nt < 4; ++nt) st[mt][nt] = MFMA(kf[mt], qf[nt], st[mt][nt]);
  }
  __syncthreads();  // VT complete

  // softmax over k (rows of S^T) for each column i = nt*16 + r16
#pragma unroll
  for (int nt = 0; nt < 4; ++nt) {
    float mx = -1e30f;
#pragma unroll
    for (int mt = 0; mt < 4; ++mt)
#pragma unroll
      for (int j = 0; j < 4; ++j) mx = fmaxf(mx, st[mt][nt][j]);
    mx = fmaxf(mx, __shfl_xor(mx, 16, 64));
    mx = fmaxf(mx, __shfl_xor(mx, 32, 64));
    float sum = 0.f;
#pragma unroll
    for (int mt = 0; mt < 4; ++mt)
#pragma unroll
      for (int j = 0; j < 4; ++j) {
        float p = __expf(st[mt][nt][j] - mx);
        st[mt][nt][j] = p;
        sum += p;
      }
    sum += __shfl_xor(sum, 16, 64);
    sum += __shfl_xor(sum, 32, 64);
    float inv = 1.0f / sum;
#pragma unroll
    for (int mt = 0; mt < 4; ++mt) {
      s16x4 pv;
#pragma unroll
      for (int j = 0; j < 4; ++j) pv[j] = f2bf(st[mt][nt][j] * inv);
      *(s16x4*)(P + (nt * 16 + r16) * 72 + mt * 16 + hi * 4) = pv;  // P[i][k], ds_write_b64
    }
  }
  __syncthreads();  // P complete

  // O^T = gemm_bt(VT, P): D[m=w][n=i], contraction over k
  f32x4 ot[4][4];
#pragma unroll
  for (int i = 0; i < 4; ++i)
#pragma unroll
    for (int j = 0; j < 4; ++j) ot[i][j] = (f32x4){0.f, 0.f, 0.f, 0.f};
#pragma unroll
  for (int kc = 0; kc < 2; ++kc) {
    s16x8 vf[4], pf[4];
#pragma unroll
    for (int wt = 0; wt < 4; ++wt) vf[wt] = *(const s16x8*)(VT + (wt * 16 + r16) * 72 + kc * 32 + hi * 8);
#pragma unroll
    for (int nt = 0; nt < 4; ++nt) pf[nt] = *(const s16x8*)(P + (nt * 16 + r16) * 72 + kc * 32 + hi * 8);
#pragma unroll
    for (int wt = 0; wt < 4; ++wt)
#pragma unroll
      for (int nt = 0; nt < 4; ++nt) ot[wt][nt] = MFMA(vf[wt], pf[nt], ot[wt][nt]);
  }

  // out channel permutation from transpose(0,2,1,3,4): ch=(head*32+c) -> c*16+head
  int cho = (ch & 31) * 16 + (ch >> 5);
  short* os = o + ((size_t)n * 512 + cho) * 4096;
#pragma unroll
  for (int wt = 0; wt < 4; ++wt)
#pragma unroll
    for (int nt = 0; nt < 4; ++nt) {
      int i = nt * 16 + r16;
      int w = wt * 16 + (hi << 2);
      s16x4 v;
#pragma unroll
      for (int j = 0; j < 4; ++j) v[j] = f2bf(ot[wt][nt][j]);
      *(s16x4*)(os + i * 64 + w) = v;  // 8B store, contiguous w
    }
}

// ---------------- transpose attention output: NCHW bf16 -> NHWC bf16 ----------------
__global__ __launch_bounds__(256) void transpose_o(const short* __restrict__ o, short* __restrict__ onhwc) {
  int b = blockIdx.x; int n = b >> 6; int h = b & 63;
  int t = threadIdx.x; int l = t & 63; int wv = t >> 6;
  const short* os = o + (size_t)n * (512 * 4096) + h * 64 + l;
  short* od = onhwc + (((size_t)n * 64 + h) * 64 + l) * 512;
  for (int c0 = wv * 8; c0 < 512; c0 += 32) {
    s16x8 v;
#pragma unroll
    for (int j = 0; j < 8; ++j) v[j] = os[(size_t)(c0 + j) * 4096];
    *(s16x8*)(od + c0) = v;
  }
}

// ---------------- proj 1x1 conv: GEMM M=65536, N=512, K=512 -> f32 NCHW out ----------------
__global__ __launch_bounds__(256, 2) void proj_gemm(const short* __restrict__ A, const short* __restrict__ W,
                                                    const float* __restrict__ pb, float* __restrict__ out) {
  __shared__ short Alds[128 * 32];
  __shared__ short Blds[128 * 32];
  int bid = blockIdx.x;
  int ntile = bid & 3, mtile = bid >> 2;
  int s0 = mtile * 128, co0 = ntile * 128;
  int t = threadIdx.x, l = t & 63, wv = t >> 6;
  int rl = l >> 2, kq = l & 3;
  size_t bA0 = (size_t)(s0 + wv * 16 + rl) * 512 + kq * 8;
  size_t bA1 = bA0 + (size_t)64 * 512;
  size_t bB0 = (size_t)(co0 + wv * 16 + rl) * 512 + kq * 8;
  size_t bB1 = bB0 + (size_t)64 * 512;
  short* lA0 = Alds + wv * 16 * 32;
  short* lA1 = Alds + (64 + wv * 16) * 32;
  short* lB0 = Blds + wv * 16 * 32;
  short* lB1 = Blds + (64 + wv * 16) * 32;
  int wm = wv >> 1, wn = wv & 1;
  int la = (wm * 64 + (l & 15)) * 32 + (l >> 4) * 8;
  int lb = (wn * 64 + (l & 15)) * 32 + (l >> 4) * 8;

  f32x4 acc[4][4];
#pragma unroll
  for (int i = 0; i < 4; ++i)
#pragma unroll
    for (int j = 0; j < 4; ++j) acc[i][j] = (f32x4){0.f, 0.f, 0.f, 0.f};

  for (int cs = 0; cs < 16; ++cs) {
    int o = cs * 32;
    gll16(A + bA0 + o, lA0);
    gll16(A + bA1 + o, lA1);
    gll16(W + bB0 + o, lB0);
    gll16(W + bB1 + o, lB1);
    __syncthreads();
    s16x8 af[4], bf[4];
#pragma unroll
    for (int mt = 0; mt < 4; ++mt) af[mt] = *(const s16x8*)(Alds + la + mt * 16 * 32);
#pragma unroll
    for (int nt = 0; nt < 4; ++nt) bf[nt] = *(const s16x8*)(Blds + lb + nt * 16 * 32);
#pragma unroll
    for (int mt = 0; mt < 4; ++mt)
#pragma unroll
      for (int nt = 0; nt < 4; ++nt) acc[mt][nt] = MFMA(af[mt], bf[nt], acc[mt][nt]);
    __syncthreads();
  }
#pragma unroll
  for (int mt = 0; mt < 4; ++mt) {
    int srow = s0 + wm * 64 + mt * 16 + ((l >> 4) << 2);
    int n = srow >> 12, sl = srow & 4095;
#pragma unroll
    for (int nt = 0; nt < 4; ++nt) {
      int col = co0 + wn * 64 + nt * 16 + (l & 15);
      float bias = pb[col];
      f32x4 v;
#pragma unroll
      for (int j = 0; j < 4; ++j) v[j] = acc[mt][nt][j] + bias;
      *(f32x4*)(out + ((size_t)n * 512 + col) * 4096 + sl) = v;  // float4 store
    }
  }
}

extern "C" void kernel_launch(void* const* d_in, const int* in_sizes, int n_in,
                              void* d_out, int out_size, void* d_ws, size_t ws_size,
                              hipStream_t stream) {
  const float* x   = (const float*)d_in[0];
  const float* qw  = (const float*)d_in[1];
  const float* qb  = (const float*)d_in[2];
  const float* kvw = (const float*)d_in[3];
  const float* kvb = (const float*)d_in[4];
  const float* pw  = (const float*)d_in[5];
  const float* pb  = (const float*)d_in[6];

  char* ws = (char*)d_ws;
  short* xp    = (short*)(ws);               // 71,368,704 B : padded NHWC bf16 x
  short* wqkv  = (short*)(ws + 71368704);    // 14,155,776 B : packed qkv conv weights
  short* qkv   = (short*)(ws + 85524480);    // 201,326,592 B: conv out, NCHW bf16 (q|k|v)
  short* wproj = (short*)(ws + 286851072);   //    524,288 B : packed proj weights
  short* o_nchw = (short*)d_out;             // reuse d_out front as bf16 attn-out scratch
  short* o_nhwc = xp;                        // reuse xp region (conv done by then)
  float* out = (float*)d_out;

  hipMemsetAsync(xp, 0, 71368704, stream);   // zero padding border
  pack_x<<<1024, 256, 0, stream>>>(x, xp);
  pack_w<<<1536, 256, 0, stream>>>(qw, kvw, wqkv);
  pack_pw<<<1024, 256, 0, stream>>>(pw, wproj);
  conv_gemm<<<6144, 256, 0, stream>>>(xp, wqkv, qb, kvb, qkv);
  attn<<<8192, 64, 0, stream>>>(qkv, o_nchw);
  transpose_o<<<1024, 256, 0, stream>>>(o_nchw, o_nhwc);
  proj_gemm<<<2048, 256, 0, stream>>>(o_nhwc, wproj, pb, out);
}

// Round 3
// 1187.258 us; speedup vs baseline: 1.5244x; 1.5244x over previous
//
#include <hip/hip_runtime.h>
#include <stdint.h>

typedef short s16x4 __attribute__((ext_vector_type(4)));
typedef short s16x8 __attribute__((ext_vector_type(8)));
typedef float f32x4 __attribute__((ext_vector_type(4)));

__device__ __forceinline__ short f2bf(float f) {
  unsigned u = __builtin_bit_cast(unsigned, f);
  u += 0x7fffu + ((u >> 16) & 1u);   // RNE
  return (short)(u >> 16);
}

__device__ __forceinline__ void gll16(const short* g, short* l) {
  __builtin_amdgcn_global_load_lds(
      (const __attribute__((address_space(1))) unsigned*)g,
      (__attribute__((address_space(3))) unsigned*)l, 16, 0, 0);
}

#define MFMA(a, b, c) __builtin_amdgcn_mfma_f32_16x16x32_bf16(a, b, c, 0, 0, 0)

// ---------------- pack x: NCHW f32 -> padded NHWC bf16 (16,66,66,512) ----------------
__global__ __launch_bounds__(256) void pack_x(const float* __restrict__ x, short* __restrict__ xp) {
  int b = blockIdx.x; int n = b >> 6; int h = b & 63;
  int t = threadIdx.x; int l = t & 63; int wv = t >> 6;
  const float* xs = x + (size_t)n * (512 * 4096) + h * 64 + l;
  short* xd = xp + (((size_t)n * 66 + (h + 1)) * 66 + (l + 1)) * 512;
  for (int c0 = wv * 8; c0 < 512; c0 += 32) {
    s16x8 v;
#pragma unroll
    for (int j = 0; j < 8; ++j) v[j] = f2bf(xs[(size_t)(c0 + j) * 4096]);
    *(s16x8*)(xd + c0) = v;
  }
}

// ---------------- pack conv weights: [co][ci][3][3] f32 -> [co][kyx*512+ci] bf16 ----------------
__global__ __launch_bounds__(256) void pack_w(const float* __restrict__ qw, const float* __restrict__ kvw,
                                              short* __restrict__ wqkv) {
  int co = blockIdx.x;  // 0..1535
  const float* src = (co < 512) ? (qw + (size_t)co * 4608) : (kvw + (size_t)(co - 512) * 4608);
  short* dst = wqkv + (size_t)co * 4608;
  for (int i = threadIdx.x; i < 4608; i += 256) {
    int ci = i / 9, kyx = i - ci * 9;
    dst[kyx * 512 + ci] = f2bf(src[i]);
  }
}

__global__ __launch_bounds__(256) void pack_pw(const float* __restrict__ pw, short* __restrict__ wp) {
  int i = blockIdx.x * 256 + threadIdx.x;  // grid 1024 * 256 = 262144
  wp[i] = f2bf(pw[i]);
}

// ---------------- fused qkv conv3x3 as implicit GEMM, 256x256 tile, BK=64 pipeline ----------------
// M = 65536 spatial, N = 1536 out-channels, K = 4608 (kyx*512+ci), 72 K-tiles of 64.
// 8 waves (2M x 4N), per-wave C = 128x64. LDS: 2 dbuf x (A 32KB + B 32KB) = 128KB.
// LDS rows are 128B with chunk^(row&7) XOR swizzle (conflict-free ds_read_b128);
// swizzle is pre-applied on the per-thread GLOBAL source so global_load_lds stays linear.
__global__ __launch_bounds__(512, 2) void conv_gemm(const short* __restrict__ xp, const short* __restrict__ wqkv,
                                                    const float* __restrict__ qb, const float* __restrict__ kvb,
                                                    short* __restrict__ qkv) {
  extern __shared__ short lds[];
  const int NT = 72;
  int bid = blockIdx.x;
  int swz = (bid & 7) * 192 + (bid >> 3);        // bijective XCD swizzle (1536 % 8 == 0)
  int mt = swz / 6, ntile = swz - mt * 6;        // nt fastest: each XCD owns 32 contiguous M-panels
  int s0 = mt << 8, co0 = ntile << 8;
  int t = threadIdx.x, l = t & 63, wv = t >> 6;
  int r = l & 15, kq = l >> 4;
  int wm = wv >> 2, wn = wv & 3;

  // ---- staging source offsets (elements); k16 chunk pre-XOR'd so LDS content is swizzled ----
  int trow = t >> 3;                  // 0..63 (row within a 64-row load slot)
  int k16 = (t & 7) ^ (trow & 7);
  int asrcO[4], bsrcO[4];
#pragma unroll
  for (int i = 0; i < 4; ++i) {       // i = slot: rows i*64 .. i*64+63 of the 256-row tile
    int row = i * 64 + trow;
    int s = s0 + row;
    int nn = s >> 12, hh = (s >> 6) & 63, ww = s & 63;
    asrcO[i] = ((nn * 66 + hh) * 66 + ww) * 512 + k16 * 8;
    bsrcO[i] = (co0 + row) * 4608 + k16 * 8;
  }
  int ldsStA = (wv << 10);            // bytes; + d*32768 + i*8192 (wave-uniform for gll16)
  int ldsStB = 65536 + (wv << 10);

  // ---- fragment read bases (bytes) ----
  int aRB = (wm << 14) + (r << 7);                                  // A half wm, lane row r
  int bRB = 65536 + ((wn >> 1) << 14) + ((((wn & 1) << 6) + r) << 7);
  int cb[2] = { (kq ^ (r & 7)) << 4, ((4 + kq) ^ (r & 7)) << 4 };   // swizzled k-chunk byte

  f32x4 acc[8][4];
#pragma unroll
  for (int i = 0; i < 8; ++i)
#pragma unroll
    for (int j = 0; j < 4; ++j) acc[i][j] = (f32x4){0.f, 0.f, 0.f, 0.f};

  // ---- prologue: stage tiles 0 and 1 ----
#pragma unroll
  for (int d = 0; d < 2; ++d) {
    int aoff = (d & 7) * 64;          // kyx==0 for tiles 0,1
    int boff = d * 64;
#pragma unroll
    for (int i = 0; i < 4; ++i) {
      gll16(xp + asrcO[i] + aoff, lds + ((ldsStA + (d << 15) + (i << 13)) >> 1));
      gll16(wqkv + bsrcO[i] + boff, lds + ((ldsStB + (d << 15) + (i << 13)) >> 1));
    }
  }
  asm volatile("s_waitcnt vmcnt(8)" ::: "memory");   // tile 0 landed; tile 1 in flight
  __builtin_amdgcn_s_barrier();
  __builtin_amdgcn_sched_barrier(0);

  for (int kt = 0; kt < NT; ++kt) {
    int d = kt & 1;
    int dA = aRB + (d << 15);
    int dB = bRB + (d << 15);
    s16x8 af[4][2], b0[2][2], b1[2][2];

    // ---- phase 0: read af(qm=0) + b(qn=0); MFMA quadrant (0,0) ----
#pragma unroll
    for (int m = 0; m < 4; ++m)
#pragma unroll
      for (int kc = 0; kc < 2; ++kc)
        af[m][kc] = *(const s16x8*)(lds + ((dA + (m << 11) + cb[kc]) >> 1));
#pragma unroll
    for (int n = 0; n < 2; ++n)
#pragma unroll
      for (int kc = 0; kc < 2; ++kc)
        b0[n][kc] = *(const s16x8*)(lds + ((dB + (n << 11) + cb[kc]) >> 1));
    __builtin_amdgcn_s_setprio(1);
#pragma unroll
    for (int m = 0; m < 4; ++m)
#pragma unroll
      for (int n = 0; n < 2; ++n)
#pragma unroll
        for (int kc = 0; kc < 2; ++kc) acc[m][n] = MFMA(af[m][kc], b0[n][kc], acc[m][n]);
    __builtin_amdgcn_s_setprio(0);

    // ---- phase 1: read b(qn=1); MFMA quadrant (0,1) ----
#pragma unroll
    for (int n = 0; n < 2; ++n)
#pragma unroll
      for (int kc = 0; kc < 2; ++kc)
        b1[n][kc] = *(const s16x8*)(lds + ((dB + 4096 + (n << 11) + cb[kc]) >> 1));
    __builtin_amdgcn_s_setprio(1);
#pragma unroll
    for (int m = 0; m < 4; ++m)
#pragma unroll
      for (int n = 0; n < 2; ++n)
#pragma unroll
        for (int kc = 0; kc < 2; ++kc) acc[m][2 + n] = MFMA(af[m][kc], b1[n][kc], acc[m][2 + n]);
    __builtin_amdgcn_s_setprio(0);

    // ---- phase 2: read af(qm=1); all reads of buf[d] now done -> stage tile kt+2 into it ----
#pragma unroll
    for (int m = 0; m < 4; ++m)
#pragma unroll
      for (int kc = 0; kc < 2; ++kc)
        af[m][kc] = *(const s16x8*)(lds + ((dA + 8192 + (m << 11) + cb[kc]) >> 1));
    asm volatile("s_waitcnt lgkmcnt(0)" ::: "memory");  // this wave's reads of buf[d] complete
    __builtin_amdgcn_s_barrier();                        // ALL waves' reads of buf[d] complete
    __builtin_amdgcn_sched_barrier(0);
    if (kt + 2 < NT) {
      int k2 = kt + 2;
      int kyx = k2 >> 3; int ky = kyx / 3; int kx = kyx - ky * 3;
      int aoff = (ky * 66 + kx) * 512 + (k2 & 7) * 64;
      int boff = k2 * 64;
#pragma unroll
      for (int i = 0; i < 4; ++i) {
        gll16(xp + asrcO[i] + aoff, lds + ((ldsStA + (d << 15) + (i << 13)) >> 1));
        gll16(wqkv + bsrcO[i] + boff, lds + ((ldsStB + (d << 15) + (i << 13)) >> 1));
      }
    }
    __builtin_amdgcn_s_setprio(1);
#pragma unroll
    for (int m = 0; m < 4; ++m)
#pragma unroll
      for (int n = 0; n < 2; ++n)
#pragma unroll
        for (int kc = 0; kc < 2; ++kc) acc[4 + m][2 + n] = MFMA(af[m][kc], b1[n][kc], acc[4 + m][2 + n]);
    __builtin_amdgcn_s_setprio(0);

    // ---- phase 3: MFMA quadrant (1,0); counted vmcnt (never 0 mid-loop) ----
    __builtin_amdgcn_s_setprio(1);
#pragma unroll
    for (int m = 0; m < 4; ++m)
#pragma unroll
      for (int n = 0; n < 2; ++n)
#pragma unroll
        for (int kc = 0; kc < 2; ++kc) acc[4 + m][n] = MFMA(af[m][kc], b0[n][kc], acc[4 + m][n]);
    __builtin_amdgcn_s_setprio(0);
    if (kt + 2 < NT) {
      asm volatile("s_waitcnt vmcnt(8)" ::: "memory");   // tile kt+1 landed; kt+2 in flight
    } else if (kt + 1 < NT) {
      asm volatile("s_waitcnt vmcnt(0)" ::: "memory");   // drain for final tile
    }
    __builtin_amdgcn_s_barrier();
    __builtin_amdgcn_sched_barrier(0);
  }

  // ---- epilogue: bias + bf16 store to NCHW qkv ----
#pragma unroll
  for (int m8 = 0; m8 < 8; ++m8) {
    int srow = s0 + wm * 128 + m8 * 16 + kq * 4;
    int nn = srow >> 12, sl = srow & 4095;
#pragma unroll
    for (int n4 = 0; n4 < 4; ++n4) {
      int col = co0 + wn * 64 + n4 * 16 + r;
      float bias = (col < 512) ? qb[col] : kvb[col - 512];
      s16x4 v;
#pragma unroll
      for (int j = 0; j < 4; ++j) v[j] = f2bf(acc[m8][n4][j] + bias);
      *(s16x4*)(qkv + ((size_t)nn * 1536 + col) * 4096 + sl) = v;
    }
  }
}

// ---------------- per-(n,ch) attention: O = softmax(Q K^T) V on 64x64 planes ----------------
__global__ __launch_bounds__(64) void attn(const short* __restrict__ qkv, short* __restrict__ o) {
  __shared__ short VT[64 * 72];  // V^T, pitch 72
  __shared__ short P[64 * 72];   // softmax(S) as [i][k]
  int slice = blockIdx.x;
  int n = slice >> 9, ch = slice & 511;
  const short* Q = qkv + ((size_t)n * 1536 + ch) * 4096;
  const short* K = qkv + ((size_t)n * 1536 + 512 + ch) * 4096;
  const short* V = qkv + ((size_t)n * 1536 + 1024 + ch) * 4096;
  int l = threadIdx.x;
  int r16 = l & 15, hi = l >> 4;

  s16x8 vr[8];
#pragma unroll
  for (int j = 0; j < 8; ++j) vr[j] = *(const s16x8*)(V + l * 64 + j * 8);
#pragma unroll
  for (int a = 0; a < 8; ++a)
#pragma unroll
    for (int e = 0; e < 8; ++e) VT[(a * 8 + e) * 72 + l] = vr[a][e];

  f32x4 st[4][4];
#pragma unroll
  for (int i = 0; i < 4; ++i)
#pragma unroll
    for (int j = 0; j < 4; ++j) st[i][j] = (f32x4){0.f, 0.f, 0.f, 0.f};
#pragma unroll
  for (int kc = 0; kc < 2; ++kc) {
    s16x8 kf[4], qf[4];
#pragma unroll
    for (int mt = 0; mt < 4; ++mt) kf[mt] = *(const s16x8*)(K + (mt * 16 + r16) * 64 + kc * 32 + hi * 8);
#pragma unroll
    for (int nt = 0; nt < 4; ++nt) qf[nt] = *(const s16x8*)(Q + (nt * 16 + r16) * 64 + kc * 32 + hi * 8);
#pragma unroll
    for (int mt = 0; mt < 4; ++mt)
#pragma unroll
      for (int nt = 0; nt < 4; ++nt) st[mt][nt] = MFMA(kf[mt], qf[nt], st[mt][nt]);
  }
  __syncthreads();

#pragma unroll
  for (int nt = 0; nt < 4; ++nt) {
    float mx = -1e30f;
#pragma unroll
    for (int mt = 0; mt < 4; ++mt)
#pragma unroll
      for (int j = 0; j < 4; ++j) mx = fmaxf(mx, st[mt][nt][j]);
    mx = fmaxf(mx, __shfl_xor(mx, 16, 64));
    mx = fmaxf(mx, __shfl_xor(mx, 32, 64));
    float sum = 0.f;
#pragma unroll
    for (int mt = 0; mt < 4; ++mt)
#pragma unroll
      for (int j = 0; j < 4; ++j) {
        float p = __expf(st[mt][nt][j] - mx);
        st[mt][nt][j] = p;
        sum += p;
      }
    sum += __shfl_xor(sum, 16, 64);
    sum += __shfl_xor(sum, 32, 64);
    float inv = 1.0f / sum;
#pragma unroll
    for (int mt = 0; mt < 4; ++mt) {
      s16x4 pv;
#pragma unroll
      for (int j = 0; j < 4; ++j) pv[j] = f2bf(st[mt][nt][j] * inv);
      *(s16x4*)(P + (nt * 16 + r16) * 72 + mt * 16 + hi * 4) = pv;
    }
  }
  __syncthreads();

  f32x4 ot[4][4];
#pragma unroll
  for (int i = 0; i < 4; ++i)
#pragma unroll
    for (int j = 0; j < 4; ++j) ot[i][j] = (f32x4){0.f, 0.f, 0.f, 0.f};
#pragma unroll
  for (int kc = 0; kc < 2; ++kc) {
    s16x8 vf[4], pf[4];
#pragma unroll
    for (int wt = 0; wt < 4; ++wt) vf[wt] = *(const s16x8*)(VT + (wt * 16 + r16) * 72 + kc * 32 + hi * 8);
#pragma unroll
    for (int nt = 0; nt < 4; ++nt) pf[nt] = *(const s16x8*)(P + (nt * 16 + r16) * 72 + kc * 32 + hi * 8);
#pragma unroll
    for (int wt = 0; wt < 4; ++wt)
#pragma unroll
      for (int nt = 0; nt < 4; ++nt) ot[wt][nt] = MFMA(vf[wt], pf[nt], ot[wt][nt]);
  }

  int cho = (ch & 31) * 16 + (ch >> 5);
  short* os = o + ((size_t)n * 512 + cho) * 4096;
#pragma unroll
  for (int wt = 0; wt < 4; ++wt)
#pragma unroll
    for (int nt = 0; nt < 4; ++nt) {
      int i = nt * 16 + r16;
      int w = wt * 16 + (hi << 2);
      s16x4 v;
#pragma unroll
      for (int j = 0; j < 4; ++j) v[j] = f2bf(ot[wt][nt][j]);
      *(s16x4*)(os + i * 64 + w) = v;
    }
}

// ---------------- transpose attention output: NCHW bf16 -> NHWC bf16 ----------------
__global__ __launch_bounds__(256) void transpose_o(const short* __restrict__ o, short* __restrict__ onhwc) {
  int b = blockIdx.x; int n = b >> 6; int h = b & 63;
  int t = threadIdx.x; int l = t & 63; int wv = t >> 6;
  const short* os = o + (size_t)n * (512 * 4096) + h * 64 + l;
  short* od = onhwc + (((size_t)n * 64 + h) * 64 + l) * 512;
  for (int c0 = wv * 8; c0 < 512; c0 += 32) {
    s16x8 v;
#pragma unroll
    for (int j = 0; j < 8; ++j) v[j] = os[(size_t)(c0 + j) * 4096];
    *(s16x8*)(od + c0) = v;
  }
}

// ---------------- proj 1x1 conv: GEMM M=65536, N=512, K=512 -> f32 NCHW out ----------------
__global__ __launch_bounds__(256, 2) void proj_gemm(const short* __restrict__ A, const short* __restrict__ W,
                                                    const float* __restrict__ pb, float* __restrict__ out) {
  __shared__ short Alds[128 * 32];
  __shared__ short Blds[128 * 32];
  int bid = blockIdx.x;
  int ntile = bid & 3, mtile = bid >> 2;
  int s0 = mtile * 128, co0 = ntile * 128;
  int t = threadIdx.x, l = t & 63, wv = t >> 6;
  int rl = l >> 2, kq = l & 3;
  size_t bA0 = (size_t)(s0 + wv * 16 + rl) * 512 + kq * 8;
  size_t bA1 = bA0 + (size_t)64 * 512;
  size_t bB0 = (size_t)(co0 + wv * 16 + rl) * 512 + kq * 8;
  size_t bB1 = bB0 + (size_t)64 * 512;
  short* lA0 = Alds + wv * 16 * 32;
  short* lA1 = Alds + (64 + wv * 16) * 32;
  short* lB0 = Blds + wv * 16 * 32;
  short* lB1 = Blds + (64 + wv * 16) * 32;
  int wm = wv >> 1, wn = wv & 1;
  int la = (wm * 64 + (l & 15)) * 32 + (l >> 4) * 8;
  int lb = (wn * 64 + (l & 15)) * 32 + (l >> 4) * 8;

  f32x4 acc[4][4];
#pragma unroll
  for (int i = 0; i < 4; ++i)
#pragma unroll
    for (int j = 0; j < 4; ++j) acc[i][j] = (f32x4){0.f, 0.f, 0.f, 0.f};

  for (int cs = 0; cs < 16; ++cs) {
    int o = cs * 32;
    gll16(A + bA0 + o, lA0);
    gll16(A + bA1 + o, lA1);
    gll16(W + bB0 + o, lB0);
    gll16(W + bB1 + o, lB1);
    __syncthreads();
    s16x8 af[4], bf[4];
#pragma unroll
    for (int mt = 0; mt < 4; ++mt) af[mt] = *(const s16x8*)(Alds + la + mt * 16 * 32);
#pragma unroll
    for (int nt = 0; nt < 4; ++nt) bf[nt] = *(const s16x8*)(Blds + lb + nt * 16 * 32);
#pragma unroll
    for (int mt = 0; mt < 4; ++mt)
#pragma unroll
      for (int nt = 0; nt < 4; ++nt) acc[mt][nt] = MFMA(af[mt], bf[nt], acc[mt][nt]);
    __syncthreads();
  }
#pragma unroll
  for (int mt = 0; mt < 4; ++mt) {
    int srow = s0 + wm * 64 + mt * 16 + ((l >> 4) << 2);
    int n = srow >> 12, sl = srow & 4095;
#pragma unroll
    for (int nt = 0; nt < 4; ++nt) {
      int col = co0 + wn * 64 + nt * 16 + (l & 15);
      float bias = pb[col];
      f32x4 v;
#pragma unroll
      for (int j = 0; j < 4; ++j) v[j] = acc[mt][nt][j] + bias;
      *(f32x4*)(out + ((size_t)n * 512 + col) * 4096 + sl) = v;
    }
  }
}

extern "C" void kernel_launch(void* const* d_in, const int* in_sizes, int n_in,
                              void* d_out, int out_size, void* d_ws, size_t ws_size,
                              hipStream_t stream) {
  const float* x   = (const float*)d_in[0];
  const float* qw  = (const float*)d_in[1];
  const float* qb  = (const float*)d_in[2];
  const float* kvw = (const float*)d_in[3];
  const float* kvb = (const float*)d_in[4];
  const float* pw  = (const float*)d_in[5];
  const float* pb  = (const float*)d_in[6];

  char* ws = (char*)d_ws;
  short* xp    = (short*)(ws);               // 71,368,704 B : padded NHWC bf16 x
  short* wqkv  = (short*)(ws + 71368704);    // 14,155,776 B : packed qkv conv weights
  short* qkv   = (short*)(ws + 85524480);    // 201,326,592 B: conv out, NCHW bf16 (q|k|v)
  short* wproj = (short*)(ws + 286851072);   //    524,288 B : packed proj weights
  short* o_nchw = (short*)d_out;             // reuse d_out front as bf16 attn-out scratch
  short* o_nhwc = xp;                        // reuse xp region (conv done by then)
  float* out = (float*)d_out;

  // Host-side attribute set; unconditional (no static guards — harness rule),
  // does not enqueue onto the stream so it is graph-capture-safe.
  hipFuncSetAttribute(reinterpret_cast<const void*>(conv_gemm),
                      hipFuncAttributeMaxDynamicSharedMemorySize, 131072);

  hipMemsetAsync(xp, 0, 71368704, stream);   // zero padding border
  pack_x<<<1024, 256, 0, stream>>>(x, xp);
  pack_w<<<1536, 256, 0, stream>>>(qw, kvw, wqkv);
  pack_pw<<<1024, 256, 0, stream>>>(pw, wproj);
  conv_gemm<<<1536, 512, 131072, stream>>>(xp, wqkv, qb, kvb, qkv);
  attn<<<8192, 64, 0, stream>>>(qkv, o_nchw);
  transpose_o<<<1024, 256, 0, stream>>>(o_nchw, o_nhwc);
  proj_gemm<<<2048, 256, 0, stream>>>(o_nhwc, wproj, pb, out);
}